// Round 15
// baseline (177.193 us; speedup 1.0000x reference)
//
#include <hip/hip_runtime.h>
#include <hip/hip_bf16.h>

#define NCH 64
#define SPAN 64            // dst nodes per bucket (dl fits in 6 bits)
#define NBIN 256           // binning blocks (fused kernel, low half)
#define NGEMM 768          // gemm blocks   (fused kernel, high half)
#define FUSE_THREADS 512   // 8 waves/block
#define NB_CAP 1536        // bucket slot capacity AND LDS stage capacity
                           // (lambda~1023, sigma~32 -> P(>1536) ~ 0 at 16sigma;
                           //  overflow list keeps adversarial inputs correct)

// ---------------------------------------------------------------------------
// Block 0: dtype detection (flags[0]=fp32?, flags[1]=int64?) + zero the
// overflow cursor flags[2]. Other blocks: zero gcnt (ws poisoned 0xAA).
// gcnt doubles as the bucket placement cursor (round-12 winner: no hist/scan).
// ---------------------------------------------------------------------------
__global__ void detect_init_kernel(const unsigned short* __restrict__ gp, int n16,
                                   const unsigned* __restrict__ ip, int niw,
                                   unsigned* __restrict__ flags,
                                   unsigned* __restrict__ gcnt, int nb) {
    if (blockIdx.x == 0) {
        __shared__ unsigned se, so;
        if (threadIdx.x == 0) { se = 0u; so = 0u; flags[2] = 0u; }
        __syncthreads();
        unsigned le = 0u, lo = 0u;
        // fp32 viewed as shorts: ~12.5% show "bf16 exponent" >= 0xC0 (|x|>=2^65).
        // Genuine bf16 N(0,1): none.
        for (int i = threadIdx.x; i < n16; i += blockDim.x) {
            unsigned ex = (unsigned)((gp[i] >> 7) & 0xFFu);
            if (ex >= 0xC0u) le++;
        }
        // int64 ids (<2^31): every odd 32-bit word is 0. int32 ids: not.
        for (int i = threadIdx.x; i < niw; i += blockDim.x) {
            if ((i & 1) && ip[i] != 0u) lo++;
        }
        atomicAdd(&se, le);
        atomicAdd(&so, lo);
        __syncthreads();
        if (threadIdx.x == 0) {
            flags[0] = (se > 50u) ? 1u : 0u;
            flags[1] = (so < 50u) ? 1u : 0u;
        }
    } else {
        const int stride = (gridDim.x - 1) * blockDim.x;
        for (int i = (blockIdx.x - 1) * blockDim.x + threadIdx.x; i < nb; i += stride)
            gcnt[i] = 0u;
    }
}

// ---------------------------------------------------------------------------
// FUSED kernel. Blocks [0,NBIN): binning into FIXED-CAPACITY bucket slots,
// round-15: VECTORIZED edge loads (longlong2 = 2 int64 edges / int4 = 4
// int32 edges per 16B issue — issue-width lever, same as round-14's gather
// win). Blocks [NBIN,NBIN+NGEMM): edge-MLP GEMM with cooperative LDS
// staging (round-13 lesson: staging IS the win), round-15: 8 rows per
// wave-iteration at 16B/lane (2x bytes per issue round, niter 5 -> 3).
// __launch_bounds__(512,4): round-4 lesson — (512,8) spills w[64] to scratch.
// Round-9/10 lessons: no coop grid.sync; no dedicated wide binning grid.
// ---------------------------------------------------------------------------
__global__ __launch_bounds__(FUSE_THREADS, 4)
void binning_gemm_kernel(const void* __restrict__ srcp, const void* __restrict__ dstp,
                         unsigned* __restrict__ gcnt, unsigned* __restrict__ binned,
                         unsigned long long* __restrict__ ovbuf,
                         unsigned* __restrict__ flags, int n_edges, int nb,
                         int depth,
                         const void* __restrict__ Gp, const void* __restrict__ Rp,
                         const void* __restrict__ Wp, const void* __restrict__ bp,
                         void* __restrict__ PQ, int n_nodes) {
    extern __shared__ unsigned lds[];
    if (blockIdx.x < NBIN) {
        // ------------------------- binning path ---------------------------
        unsigned* lcnt = lds;               // [nb]
        unsigned* stage = lds + nb;         // [nb*depth]
        for (int i = threadIdx.x; i < nb; i += blockDim.x) lcnt[i] = 0u;
        __syncthreads();
        const unsigned i64 = flags[1];
        // chunk multiple of 4 -> e0 16B-aligned for int4/longlong2 loads
        const int chunk = (((n_edges + NBIN - 1) / NBIN) + 3) & ~3;
        const int e0 = blockIdx.x * chunk;
        const int e1 = min(e0 + chunk, n_edges);

        auto put = [&](int s, int d) {
            const int bkt = d >> 6;
            const unsigned pk = ((unsigned)(d & 63) << 26) | (unsigned)s;
            unsigned pos = atomicAdd(&lcnt[bkt], 1u);
            if ((int)pos < depth) {
                stage[bkt * depth + (int)pos] = pk;
            } else {
                unsigned g = atomicAdd(&gcnt[bkt], 1u);
                if (g < NB_CAP) {
                    binned[bkt * NB_CAP + g] = pk;
                } else {
                    unsigned oi = atomicAdd(&flags[2], 1u);
                    ovbuf[oi] = ((unsigned long long)(unsigned)d << 32) |
                                (unsigned long long)(unsigned)s;
                }
            }
        };

        if (e1 > e0) {
            if (i64) {
                const longlong2* s2 = (const longlong2*)((const long long*)srcp + e0);
                const longlong2* d2 = (const longlong2*)((const long long*)dstp + e0);
                const int npair = (e1 - e0) >> 1;
                for (int i = threadIdx.x; i < npair; i += blockDim.x) {
                    const longlong2 sv = s2[i];
                    const longlong2 dv = d2[i];
                    put((int)sv.x, (int)dv.x);
                    put((int)sv.y, (int)dv.y);
                }
                for (int e = e0 + npair * 2 + threadIdx.x; e < e1; e += blockDim.x)
                    put((int)((const long long*)srcp)[e],
                        (int)((const long long*)dstp)[e]);
            } else {
                const int4* s4 = (const int4*)((const int*)srcp + e0);
                const int4* d4 = (const int4*)((const int*)dstp + e0);
                const int nquad = (e1 - e0) >> 2;
                for (int i = threadIdx.x; i < nquad; i += blockDim.x) {
                    const int4 sv = s4[i];
                    const int4 dv = d4[i];
                    put(sv.x, dv.x);
                    put(sv.y, dv.y);
                    put(sv.z, dv.z);
                    put(sv.w, dv.w);
                }
                for (int e = e0 + nquad * 4 + threadIdx.x; e < e1; e += blockDim.x)
                    put(((const int*)srcp)[e], ((const int*)dstp)[e]);
            }
        }
        __syncthreads();
        for (int bkt = threadIdx.x; bkt < nb; bkt += blockDim.x) {
            int k = min((int)lcnt[bkt], depth);
            if (k > 0) {
                unsigned base = atomicAdd(&gcnt[bkt], (unsigned)k);
                for (int i = 0; i < k; ++i) {
                    const unsigned pk = stage[bkt * depth + i];
                    const unsigned pos = base + (unsigned)i;
                    if (pos < NB_CAP) {
                        binned[bkt * NB_CAP + pos] = pk;
                    } else {
                        const unsigned d = (unsigned)(bkt * SPAN) + (pk >> 26);
                        unsigned oi = atomicAdd(&flags[2], 1u);
                        ovbuf[oi] = ((unsigned long long)d << 32) |
                                    (unsigned long long)(pk & 0x03FFFFFFu);
                    }
                }
            }
        }
    } else {
        // ------- gemm path: cooperative staging, 8 rows / wave-iter --------
        const unsigned f32 = flags[0];
        const int lane = threadIdx.x & 63;
        const int waveInBlk = threadIdx.x >> 6;
        const int gwave = (blockIdx.x - NBIN) * 8 + waveInBlk;
        const int nwaves = NGEMM * 8;
        const int n_rows = 2 * n_nodes;
        const int ngroups = (n_rows + 7) / 8;

        float* ldsb = (float*)lds;                   // 16KB of the dyn LDS
        float* slot = &ldsb[waveInBlk * 8 * NCH];

        float w[NCH];
        float bias;
        if (f32) {
            const float* Wf = (const float*)Wp;
            #pragma unroll
            for (int k = 0; k < NCH; ++k) w[k] = Wf[lane * NCH + k];
            bias = ((const float*)bp)[lane];
        } else {
            const __hip_bfloat16* Wh = (const __hip_bfloat16*)Wp;
            #pragma unroll
            for (int k = 0; k < NCH; ++k) w[k] = __bfloat162float(Wh[lane * NCH + k]);
            bias = __bfloat162float(((const __hip_bfloat16*)bp)[lane]);
        }

        const int niter = (ngroups + nwaves - 1) / nwaves;
        for (int it = 0; it < niter; ++it) {
            const int grp = gwave + it * nwaves;
            const bool gvalid = (grp < ngroups);
            const int m0 = grp * 8;
            if (gvalid) {
                const int myrow = m0 + (lane >> 3);      // 8 rows x 8 lanes
                const int col = (lane & 7) * 8;          // 8 elems (16B bf16)
                float x[8];
                #pragma unroll
                for (int u = 0; u < 8; ++u) x[u] = 0.f;
                if (myrow < n_rows) {
                    const bool isQ = (myrow >= n_nodes);
                    const int r = isQ ? (myrow - n_nodes) : myrow;
                    const void* inp = isQ ? Rp : Gp;
                    if (f32) {
                        const float4* p = (const float4*)((const float*)inp +
                                                          (size_t)r * NCH + col);
                        const float4 v0 = p[0];
                        const float4 v1 = p[1];
                        x[0] = v0.x; x[1] = v0.y; x[2] = v0.z; x[3] = v0.w;
                        x[4] = v1.x; x[5] = v1.y; x[6] = v1.z; x[7] = v1.w;
                    } else {
                        const uint4 v = *(const uint4*)((const unsigned short*)inp +
                                                        (size_t)r * NCH + col);
                        x[0] = __uint_as_float(v.x << 16);
                        x[1] = __uint_as_float(v.x & 0xFFFF0000u);
                        x[2] = __uint_as_float(v.y << 16);
                        x[3] = __uint_as_float(v.y & 0xFFFF0000u);
                        x[4] = __uint_as_float(v.z << 16);
                        x[5] = __uint_as_float(v.z & 0xFFFF0000u);
                        x[6] = __uint_as_float(v.w << 16);
                        x[7] = __uint_as_float(v.w & 0xFFFF0000u);
                    }
                }
                const int sb = (lane >> 3) * NCH + col;
                #pragma unroll
                for (int u = 0; u < 8; ++u) slot[sb + u] = x[u];
            }
            __syncthreads();
            if (gvalid) {
                #pragma unroll
                for (int rr = 0; rr < 8; ++rr) {
                    const int m = m0 + rr;
                    if (m < n_rows) {
                        float a0 = 0.f, a1 = 0.f, a2 = 0.f, a3 = 0.f;
                        const float4* r4 = (const float4*)(slot + rr * NCH);
                        #pragma unroll
                        for (int q = 0; q < 16; ++q) {
                            float4 rv = r4[q];
                            a0 = fmaf(rv.x, w[4 * q + 0], a0);
                            a1 = fmaf(rv.y, w[4 * q + 1], a1);
                            a2 = fmaf(rv.z, w[4 * q + 2], a2);
                            a3 = fmaf(rv.w, w[4 * q + 3], a3);
                        }
                        float acc = (a0 + a1) + (a2 + a3);
                        if (m >= n_nodes) acc -= bias;       // Q' = RSC@W^T - b
                        if (f32) ((float*)PQ)[(size_t)m * NCH + lane] = acc;
                        else ((__hip_bfloat16*)PQ)[(size_t)m * NCH + lane] =
                                 __float2bfloat16(acc);
                    }
                }
            }
            __syncthreads();
        }
    }
}

// ---------------------------------------------------------------------------
// FUSED bucket sort + node aggregation (round-14 winner, unchanged):
// block = bucket of 64 dst nodes. Stage packed edges in LDS, in-LDS counting
// sort into per-node runs, then wave-per-node gather (8 edges in flight)
// with register accumulation (NO LDS accumulators — round-1 lesson).
// Overflow entries live in the global ovbuf list (count flags[2]).
// ---------------------------------------------------------------------------
__global__ __launch_bounds__(512)
void bucket_node_kernel(const unsigned* __restrict__ binned,
                        const unsigned* __restrict__ gcnt,
                        const unsigned long long* __restrict__ ovbuf,
                        const void* __restrict__ PQ,
                        const unsigned* __restrict__ flags,
                        void* __restrict__ outp, int n_nodes) {
    __shared__ unsigned scnt[SPAN];
    __shared__ unsigned soff[SPAN];
    __shared__ unsigned cur[SPAN];
    __shared__ unsigned stage[NB_CAP];
    __shared__ unsigned sorted[NB_CAP];

    const int b = blockIdx.x;
    const int tid = threadIdx.x;
    const int estart = b * NB_CAP;
    const int gc = (int)gcnt[b];
    const int count = (gc < NB_CAP) ? gc : NB_CAP;   // direct-region entries
    const int n_ov = (int)flags[2];                  // global overflow count

    if (tid < SPAN) scnt[tid] = 0u;
    __syncthreads();

    for (int i = tid; i < count; i += 512) {
        const unsigned pk = binned[estart + i];
        stage[i] = pk;
        atomicAdd(&scnt[pk >> 26], 1u);
    }
    __syncthreads();

    if (tid == 0) {
        unsigned run = 0u;
        #pragma unroll
        for (int i = 0; i < SPAN; ++i) { soff[i] = run; cur[i] = run; run += scnt[i]; }
    }
    __syncthreads();

    for (int i = tid; i < count; i += 512) {
        const unsigned pk = stage[i];
        const unsigned pos = atomicAdd(&cur[pk >> 26], 1u);
        sorted[pos] = pk & 0x03FFFFFFu;
    }
    __syncthreads();

    const unsigned f32 = flags[0];
    const int lane = tid & 63;
    const int wid = tid >> 6;
    const float* Pf = (const float*)PQ;
    const unsigned short* Ph = (const unsigned short*)PQ;

    for (int nn = wid; nn < SPAN; nn += 8) {
        const int n = b * SPAN + nn;
        if (n >= n_nodes) break;
        float q;
        if (f32) q = Pf[(size_t)(n_nodes + n) * NCH + lane];
        else {
            unsigned short h = Ph[(size_t)(n_nodes + n) * NCH + lane];
            q = __bfloat162float(*(__hip_bfloat16*)&h);
        }
        const int s0i = (int)soff[nn];
        const int scn = (int)scnt[nn];
        float vmax = 0.0f, vsum = 0.0f;
        int j = 0;
        for (; j + 8 <= scn; j += 8) {
            int e[8];
            #pragma unroll
            for (int u = 0; u < 8; ++u) e[u] = (int)sorted[s0i + j + u];
            float p[8];
            if (f32) {
                #pragma unroll
                for (int u = 0; u < 8; ++u) p[u] = Pf[(size_t)e[u] * NCH + lane];
            } else {
                unsigned short h[8];
                #pragma unroll
                for (int u = 0; u < 8; ++u) h[u] = Ph[(size_t)e[u] * NCH + lane];
                #pragma unroll
                for (int u = 0; u < 8; ++u)
                    p[u] = __bfloat162float(*(__hip_bfloat16*)&h[u]);
            }
            float v[8];
            #pragma unroll
            for (int u = 0; u < 8; ++u) v[u] = fmaxf(p[u] - q, 0.0f);
            vmax = fmaxf(vmax,
                         fmaxf(fmaxf(fmaxf(v[0], v[1]), fmaxf(v[2], v[3])),
                               fmaxf(fmaxf(v[4], v[5]), fmaxf(v[6], v[7]))));
            vsum += ((v[0] + v[1]) + (v[2] + v[3])) +
                    ((v[4] + v[5]) + (v[6] + v[7]));
        }
        for (; j < scn; ++j) {
            const int e = (int)sorted[s0i + j];
            float p;
            if (f32) p = Pf[(size_t)e * NCH + lane];
            else {
                unsigned short h = Ph[(size_t)e * NCH + lane];
                p = __bfloat162float(*(__hip_bfloat16*)&h);
            }
            const float v = fmaxf(p - q, 0.0f);
            vmax = fmaxf(vmax, v);
            vsum += v;
        }
        // overflow list (global; ~empty for uniform data): filter by node id
        int ext = 0;
        for (int i = 0; i < n_ov; ++i) {
            const unsigned long long ov = ovbuf[i];      // wave-uniform load
            const int d = (int)(ov >> 32);
            if (d == n) {
                const int e = (int)(ov & 0x03FFFFFFu);
                float p;
                if (f32) p = Pf[(size_t)e * NCH + lane];
                else {
                    unsigned short h = Ph[(size_t)e * NCH + lane];
                    p = __bfloat162float(*(__hip_bfloat16*)&h);
                }
                const float v = fmaxf(p - q, 0.0f);
                vmax = fmaxf(vmax, v);
                vsum += v;
                ext++;
            }
        }
        const int deg = scn + ext;
        const float avg = vsum / (float)(deg > 0 ? deg : 1);
        if (f32) {
            float* out = (float*)outp;
            out[(size_t)n * 2 * NCH + lane] = vmax;
            out[(size_t)n * 2 * NCH + NCH + lane] = avg;
        } else {
            __hip_bfloat16* out = (__hip_bfloat16*)outp;
            out[(size_t)n * 2 * NCH + lane] = __float2bfloat16(vmax);
            out[(size_t)n * 2 * NCH + NCH + lane] = __float2bfloat16(avg);
        }
    }
}

extern "C" void kernel_launch(void* const* d_in, const int* in_sizes, int n_in,
                              void* d_out, int out_size, void* d_ws, size_t ws_size,
                              hipStream_t stream) {
    const void* G = d_in[0];
    const void* RSC = d_in[1];
    const void* src = d_in[2];
    const void* dst = d_in[3];
    const void* W = d_in[4];
    const void* b = d_in[5];

    const int n_nodes = in_sizes[0] / NCH;
    const int n_edges = in_sizes[2];
    const int nb = (n_nodes + SPAN - 1) / SPAN;

    // ws layout (bytes): [flags 256][binned 4*nb*NB_CAP][ovbuf 8E]
    //                    [gcnt 4nb][PQ dtype*64*2N]
    char* ws = (char*)d_ws;
    unsigned* flags = (unsigned*)ws;
    size_t off = 256;
    unsigned* binned = (unsigned*)(ws + off);
    off += (((size_t)nb * NB_CAP * 4 + 255) / 256) * 256;
    unsigned long long* ovbuf = (unsigned long long*)(ws + off);
    off += (((size_t)n_edges * 8 + 255) / 256) * 256;
    unsigned* gcnt = (unsigned*)(ws + off);
    off += (((size_t)nb * 4 + 255) / 256) * 256;
    void* PQ = (void*)(ws + off);                   // fp32 or bf16 per flags[0]

    const int n_g_probe = (in_sizes[0] < 8192) ? in_sizes[0] : 8192;
    const int n_idx_probe = (n_edges < 8192) ? n_edges : 8192;

    detect_init_kernel<<<64, 256, 0, stream>>>((const unsigned short*)G, n_g_probe,
                                               (const unsigned*)src, n_idx_probe,
                                               flags, gcnt, nb);

    // depth sized for ~37.5K LDS -> 4 blocks/CU possible by LDS.
    int depth = 9728 / nb - 1;
    if (depth > 19) depth = 19;
    if (depth < 4) depth = 4;
    size_t bin_lds = (size_t)nb * (depth + 1) * 4;
    const size_t gemm_lds = (size_t)(FUSE_THREADS / 64) * 8 * NCH * 4;  // 16 KB
    if (bin_lds < gemm_lds) bin_lds = gemm_lds;

    binning_gemm_kernel<<<NBIN + NGEMM, FUSE_THREADS, bin_lds, stream>>>(
        src, dst, gcnt, binned, ovbuf, flags, n_edges, nb, depth,
        G, RSC, W, b, PQ, n_nodes);

    bucket_node_kernel<<<nb, 512, 0, stream>>>(binned, gcnt, ovbuf, PQ, flags,
                                               d_out, n_nodes);
}

// Round 16
// 175.035 us; speedup vs baseline: 1.0123x; 1.0123x over previous
//
#include <hip/hip_runtime.h>
#include <hip/hip_bf16.h>

#define NCH 64
#define SPAN 64            // dst nodes per bucket (dl fits in 6 bits)
#define NBIN 256           // binning blocks (fused kernel, low half)
#define NGEMM 768          // gemm blocks   (fused kernel, high half)
#define FUSE_THREADS 512   // 8 waves/block
#define NB_CAP 1536        // bucket slot capacity AND LDS stage capacity
                           // (lambda~1023, sigma~32 -> P(>1536) ~ 0 at 16sigma;
                           //  overflow list keeps adversarial inputs correct)

// ---------------------------------------------------------------------------
// Block 0: dtype detection (flags[0]=fp32?, flags[1]=int64?) + zero the
// overflow cursor flags[2]. Other blocks: zero gcnt (ws poisoned 0xAA).
// gcnt doubles as the bucket placement cursor (round-12 winner: no hist/scan).
// ---------------------------------------------------------------------------
__global__ void detect_init_kernel(const unsigned short* __restrict__ gp, int n16,
                                   const unsigned* __restrict__ ip, int niw,
                                   unsigned* __restrict__ flags,
                                   unsigned* __restrict__ gcnt, int nb) {
    if (blockIdx.x == 0) {
        __shared__ unsigned se, so;
        if (threadIdx.x == 0) { se = 0u; so = 0u; flags[2] = 0u; }
        __syncthreads();
        unsigned le = 0u, lo = 0u;
        // fp32 viewed as shorts: ~12.5% show "bf16 exponent" >= 0xC0 (|x|>=2^65).
        // Genuine bf16 N(0,1): none.
        for (int i = threadIdx.x; i < n16; i += blockDim.x) {
            unsigned ex = (unsigned)((gp[i] >> 7) & 0xFFu);
            if (ex >= 0xC0u) le++;
        }
        // int64 ids (<2^31): every odd 32-bit word is 0. int32 ids: not.
        for (int i = threadIdx.x; i < niw; i += blockDim.x) {
            if ((i & 1) && ip[i] != 0u) lo++;
        }
        atomicAdd(&se, le);
        atomicAdd(&so, lo);
        __syncthreads();
        if (threadIdx.x == 0) {
            flags[0] = (se > 50u) ? 1u : 0u;
            flags[1] = (so < 50u) ? 1u : 0u;
        }
    } else {
        const int stride = (gridDim.x - 1) * blockDim.x;
        for (int i = (blockIdx.x - 1) * blockDim.x + threadIdx.x; i < nb; i += stride)
            gcnt[i] = 0u;
    }
}

// ---------------------------------------------------------------------------
// FUSED kernel (round-14 configuration, restored — round-15 lesson: wider
// edge loads + 8-row staging were null; the 8-row LDS layout doubled write
// bank conflicts (740K -> 1.54M). 4-row staging is the measured optimum).
// Blocks [0,NBIN): binning into FIXED-CAPACITY bucket slots. Blocks
// [NBIN,NBIN+NGEMM): edge-MLP GEMM with cooperative LDS staging (round-13
// lesson: cooperative 4-rows-per-issue staging IS the win; barriers cheap).
// __launch_bounds__(512,4): round-4 lesson — (512,8) spills w[64] to scratch.
// Round-9/10 lessons: no coop grid.sync; no dedicated wide binning grid.
// ---------------------------------------------------------------------------
__global__ __launch_bounds__(FUSE_THREADS, 4)
void binning_gemm_kernel(const void* __restrict__ srcp, const void* __restrict__ dstp,
                         unsigned* __restrict__ gcnt, unsigned* __restrict__ binned,
                         unsigned long long* __restrict__ ovbuf,
                         unsigned* __restrict__ flags, int n_edges, int nb,
                         int depth,
                         const void* __restrict__ Gp, const void* __restrict__ Rp,
                         const void* __restrict__ Wp, const void* __restrict__ bp,
                         void* __restrict__ PQ, int n_nodes) {
    extern __shared__ unsigned lds[];
    if (blockIdx.x < NBIN) {
        // ------------------------- binning path ---------------------------
        unsigned* lcnt = lds;               // [nb]
        unsigned* stage = lds + nb;         // [nb*depth]
        for (int i = threadIdx.x; i < nb; i += blockDim.x) lcnt[i] = 0u;
        __syncthreads();
        const unsigned i64 = flags[1];
        const int chunk = (n_edges + NBIN - 1) / NBIN;
        const int e0 = blockIdx.x * chunk;
        const int e1 = min(e0 + chunk, n_edges);
        for (int e = e0 + threadIdx.x; e < e1; e += blockDim.x) {
            int s, d;
            if (i64) {
                s = (int)((const long long*)srcp)[e];
                d = (int)((const long long*)dstp)[e];
            } else {
                s = ((const int*)srcp)[e];
                d = ((const int*)dstp)[e];
            }
            const int bkt = d >> 6;
            const unsigned pk = ((unsigned)(d & 63) << 26) | (unsigned)s;
            unsigned pos = atomicAdd(&lcnt[bkt], 1u);
            if ((int)pos < depth) {
                stage[bkt * depth + (int)pos] = pk;
            } else {
                unsigned g = atomicAdd(&gcnt[bkt], 1u);
                if (g < NB_CAP) {
                    binned[bkt * NB_CAP + g] = pk;
                } else {
                    unsigned oi = atomicAdd(&flags[2], 1u);
                    ovbuf[oi] = ((unsigned long long)(unsigned)d << 32) |
                                (unsigned long long)(unsigned)s;
                }
            }
        }
        __syncthreads();
        for (int bkt = threadIdx.x; bkt < nb; bkt += blockDim.x) {
            int k = min((int)lcnt[bkt], depth);
            if (k > 0) {
                unsigned base = atomicAdd(&gcnt[bkt], (unsigned)k);
                for (int i = 0; i < k; ++i) {
                    const unsigned pk = stage[bkt * depth + i];
                    const unsigned pos = base + (unsigned)i;
                    if (pos < NB_CAP) {
                        binned[bkt * NB_CAP + pos] = pk;
                    } else {
                        const unsigned d = (unsigned)(bkt * SPAN) + (pk >> 26);
                        unsigned oi = atomicAdd(&flags[2], 1u);
                        ovbuf[oi] = ((unsigned long long)d << 32) |
                                    (unsigned long long)(pk & 0x03FFFFFFu);
                    }
                }
            }
        }
    } else {
        // -------------------------- gemm path -----------------------------
        const unsigned f32 = flags[0];
        const int lane = threadIdx.x & 63;
        const int waveInBlk = threadIdx.x >> 6;
        const int gwave = (blockIdx.x - NBIN) * 8 + waveInBlk;
        const int nwaves = NGEMM * 8;
        const int n_rows = 2 * n_nodes;
        const int ngroups = (n_rows + 3) / 4;

        float* ldsb = (float*)lds;                        // 8KB of the dyn LDS
        float* slot = &ldsb[waveInBlk * 4 * NCH];

        float w[NCH];
        float bias;
        if (f32) {
            const float* Wf = (const float*)Wp;
            #pragma unroll
            for (int k = 0; k < NCH; ++k) w[k] = Wf[lane * NCH + k];
            bias = ((const float*)bp)[lane];
        } else {
            const __hip_bfloat16* Wh = (const __hip_bfloat16*)Wp;
            #pragma unroll
            for (int k = 0; k < NCH; ++k) w[k] = __bfloat162float(Wh[lane * NCH + k]);
            bias = __bfloat162float(((const __hip_bfloat16*)bp)[lane]);
        }

        const int niter = (ngroups + nwaves - 1) / nwaves;
        for (int it = 0; it < niter; ++it) {
            const int grp = gwave + it * nwaves;
            const bool gvalid = (grp < ngroups);
            const int m0 = grp * 4;
            if (gvalid) {
                const int myrow = m0 + (lane >> 4);
                const int col = (lane & 15) * 4;
                float x0 = 0.f, x1 = 0.f, x2 = 0.f, x3 = 0.f;
                if (myrow < n_rows) {
                    const bool isQ = (myrow >= n_nodes);
                    const int r = isQ ? (myrow - n_nodes) : myrow;
                    const void* inp = isQ ? Rp : Gp;
                    if (f32) {
                        float4 v = *(const float4*)((const float*)inp +
                                                    (size_t)r * NCH + col);
                        x0 = v.x; x1 = v.y; x2 = v.z; x3 = v.w;
                    } else {
                        ushort4 v = *(const ushort4*)((const unsigned short*)inp +
                                                      (size_t)r * NCH + col);
                        x0 = __bfloat162float(*(__hip_bfloat16*)&v.x);
                        x1 = __bfloat162float(*(__hip_bfloat16*)&v.y);
                        x2 = __bfloat162float(*(__hip_bfloat16*)&v.z);
                        x3 = __bfloat162float(*(__hip_bfloat16*)&v.w);
                    }
                }
                const int sb = (lane >> 4) * NCH + col;
                slot[sb + 0] = x0; slot[sb + 1] = x1;
                slot[sb + 2] = x2; slot[sb + 3] = x3;
            }
            __syncthreads();
            if (gvalid) {
                #pragma unroll
                for (int rr = 0; rr < 4; ++rr) {
                    const int m = m0 + rr;
                    if (m < n_rows) {
                        float a0 = 0.f, a1 = 0.f, a2 = 0.f, a3 = 0.f;
                        const float4* r4 = (const float4*)(slot + rr * NCH);
                        #pragma unroll
                        for (int q = 0; q < 16; ++q) {
                            float4 rv = r4[q];
                            a0 = fmaf(rv.x, w[4 * q + 0], a0);
                            a1 = fmaf(rv.y, w[4 * q + 1], a1);
                            a2 = fmaf(rv.z, w[4 * q + 2], a2);
                            a3 = fmaf(rv.w, w[4 * q + 3], a3);
                        }
                        float acc = (a0 + a1) + (a2 + a3);
                        if (m >= n_nodes) acc -= bias;       // Q' = RSC@W^T - b
                        if (f32) ((float*)PQ)[(size_t)m * NCH + lane] = acc;
                        else ((__hip_bfloat16*)PQ)[(size_t)m * NCH + lane] =
                                 __float2bfloat16(acc);
                    }
                }
            }
            __syncthreads();
        }
    }
}

// ---------------------------------------------------------------------------
// FUSED bucket sort + node aggregation (round-14 winner, unchanged):
// block = bucket of 64 dst nodes. Stage packed edges in LDS, in-LDS counting
// sort into per-node runs, then wave-per-node gather (8 edges in flight)
// with register accumulation (NO LDS accumulators — round-1 lesson).
// Overflow entries live in the global ovbuf list (count flags[2]).
// ---------------------------------------------------------------------------
__global__ __launch_bounds__(512)
void bucket_node_kernel(const unsigned* __restrict__ binned,
                        const unsigned* __restrict__ gcnt,
                        const unsigned long long* __restrict__ ovbuf,
                        const void* __restrict__ PQ,
                        const unsigned* __restrict__ flags,
                        void* __restrict__ outp, int n_nodes) {
    __shared__ unsigned scnt[SPAN];
    __shared__ unsigned soff[SPAN];
    __shared__ unsigned cur[SPAN];
    __shared__ unsigned stage[NB_CAP];
    __shared__ unsigned sorted[NB_CAP];

    const int b = blockIdx.x;
    const int tid = threadIdx.x;
    const int estart = b * NB_CAP;
    const int gc = (int)gcnt[b];
    const int count = (gc < NB_CAP) ? gc : NB_CAP;   // direct-region entries
    const int n_ov = (int)flags[2];                  // global overflow count

    if (tid < SPAN) scnt[tid] = 0u;
    __syncthreads();

    for (int i = tid; i < count; i += 512) {
        const unsigned pk = binned[estart + i];
        stage[i] = pk;
        atomicAdd(&scnt[pk >> 26], 1u);
    }
    __syncthreads();

    if (tid == 0) {
        unsigned run = 0u;
        #pragma unroll
        for (int i = 0; i < SPAN; ++i) { soff[i] = run; cur[i] = run; run += scnt[i]; }
    }
    __syncthreads();

    for (int i = tid; i < count; i += 512) {
        const unsigned pk = stage[i];
        const unsigned pos = atomicAdd(&cur[pk >> 26], 1u);
        sorted[pos] = pk & 0x03FFFFFFu;
    }
    __syncthreads();

    const unsigned f32 = flags[0];
    const int lane = tid & 63;
    const int wid = tid >> 6;
    const float* Pf = (const float*)PQ;
    const unsigned short* Ph = (const unsigned short*)PQ;

    for (int nn = wid; nn < SPAN; nn += 8) {
        const int n = b * SPAN + nn;
        if (n >= n_nodes) break;
        float q;
        if (f32) q = Pf[(size_t)(n_nodes + n) * NCH + lane];
        else {
            unsigned short h = Ph[(size_t)(n_nodes + n) * NCH + lane];
            q = __bfloat162float(*(__hip_bfloat16*)&h);
        }
        const int s0i = (int)soff[nn];
        const int scn = (int)scnt[nn];
        float vmax = 0.0f, vsum = 0.0f;
        int j = 0;
        for (; j + 8 <= scn; j += 8) {
            int e[8];
            #pragma unroll
            for (int u = 0; u < 8; ++u) e[u] = (int)sorted[s0i + j + u];
            float p[8];
            if (f32) {
                #pragma unroll
                for (int u = 0; u < 8; ++u) p[u] = Pf[(size_t)e[u] * NCH + lane];
            } else {
                unsigned short h[8];
                #pragma unroll
                for (int u = 0; u < 8; ++u) h[u] = Ph[(size_t)e[u] * NCH + lane];
                #pragma unroll
                for (int u = 0; u < 8; ++u)
                    p[u] = __bfloat162float(*(__hip_bfloat16*)&h[u]);
            }
            float v[8];
            #pragma unroll
            for (int u = 0; u < 8; ++u) v[u] = fmaxf(p[u] - q, 0.0f);
            vmax = fmaxf(vmax,
                         fmaxf(fmaxf(fmaxf(v[0], v[1]), fmaxf(v[2], v[3])),
                               fmaxf(fmaxf(v[4], v[5]), fmaxf(v[6], v[7]))));
            vsum += ((v[0] + v[1]) + (v[2] + v[3])) +
                    ((v[4] + v[5]) + (v[6] + v[7]));
        }
        for (; j < scn; ++j) {
            const int e = (int)sorted[s0i + j];
            float p;
            if (f32) p = Pf[(size_t)e * NCH + lane];
            else {
                unsigned short h = Ph[(size_t)e * NCH + lane];
                p = __bfloat162float(*(__hip_bfloat16*)&h);
            }
            const float v = fmaxf(p - q, 0.0f);
            vmax = fmaxf(vmax, v);
            vsum += v;
        }
        // overflow list (global; ~empty for uniform data): filter by node id
        int ext = 0;
        for (int i = 0; i < n_ov; ++i) {
            const unsigned long long ov = ovbuf[i];      // wave-uniform load
            const int d = (int)(ov >> 32);
            if (d == n) {
                const int e = (int)(ov & 0x03FFFFFFu);
                float p;
                if (f32) p = Pf[(size_t)e * NCH + lane];
                else {
                    unsigned short h = Ph[(size_t)e * NCH + lane];
                    p = __bfloat162float(*(__hip_bfloat16*)&h);
                }
                const float v = fmaxf(p - q, 0.0f);
                vmax = fmaxf(vmax, v);
                vsum += v;
                ext++;
            }
        }
        const int deg = scn + ext;
        const float avg = vsum / (float)(deg > 0 ? deg : 1);
        if (f32) {
            float* out = (float*)outp;
            out[(size_t)n * 2 * NCH + lane] = vmax;
            out[(size_t)n * 2 * NCH + NCH + lane] = avg;
        } else {
            __hip_bfloat16* out = (__hip_bfloat16*)outp;
            out[(size_t)n * 2 * NCH + lane] = __float2bfloat16(vmax);
            out[(size_t)n * 2 * NCH + NCH + lane] = __float2bfloat16(avg);
        }
    }
}

extern "C" void kernel_launch(void* const* d_in, const int* in_sizes, int n_in,
                              void* d_out, int out_size, void* d_ws, size_t ws_size,
                              hipStream_t stream) {
    const void* G = d_in[0];
    const void* RSC = d_in[1];
    const void* src = d_in[2];
    const void* dst = d_in[3];
    const void* W = d_in[4];
    const void* b = d_in[5];

    const int n_nodes = in_sizes[0] / NCH;
    const int n_edges = in_sizes[2];
    const int nb = (n_nodes + SPAN - 1) / SPAN;

    // ws layout (bytes): [flags 256][binned 4*nb*NB_CAP][ovbuf 8E]
    //                    [gcnt 4nb][PQ dtype*64*2N]
    char* ws = (char*)d_ws;
    unsigned* flags = (unsigned*)ws;
    size_t off = 256;
    unsigned* binned = (unsigned*)(ws + off);
    off += (((size_t)nb * NB_CAP * 4 + 255) / 256) * 256;
    unsigned long long* ovbuf = (unsigned long long*)(ws + off);
    off += (((size_t)n_edges * 8 + 255) / 256) * 256;
    unsigned* gcnt = (unsigned*)(ws + off);
    off += (((size_t)nb * 4 + 255) / 256) * 256;
    void* PQ = (void*)(ws + off);                   // fp32 or bf16 per flags[0]

    const int n_g_probe = (in_sizes[0] < 8192) ? in_sizes[0] : 8192;
    const int n_idx_probe = (n_edges < 8192) ? n_edges : 8192;

    detect_init_kernel<<<64, 256, 0, stream>>>((const unsigned short*)G, n_g_probe,
                                               (const unsigned*)src, n_idx_probe,
                                               flags, gcnt, nb);

    // depth sized for ~37.5K LDS -> 4 blocks/CU possible by LDS.
    int depth = 9728 / nb - 1;
    if (depth > 19) depth = 19;
    if (depth < 4) depth = 4;
    size_t bin_lds = (size_t)nb * (depth + 1) * 4;
    const size_t gemm_lds = (size_t)(FUSE_THREADS / 64) * 4 * NCH * 4;  // 8 KB
    if (bin_lds < gemm_lds) bin_lds = gemm_lds;

    binning_gemm_kernel<<<NBIN + NGEMM, FUSE_THREADS, bin_lds, stream>>>(
        src, dst, gcnt, binned, ovbuf, flags, n_edges, nb, depth,
        G, RSC, W, b, PQ, n_nodes);

    bucket_node_kernel<<<nb, 512, 0, stream>>>(binned, gcnt, ovbuf, PQ, flags,
                                               d_out, n_nodes);
}